// Round 6
// baseline (104.857 us; speedup 1.0000x reference)
//
#include <hip/hip_runtime.h>
#include <hip/hip_bf16.h>
#include <stdint.h>

// MoEDecoder: B=64,T=256,IN=256,HID=512,OUT=256,L=2,E=16,S=1
// Fused persistent kernel, R6:
//   512 blocks x 256 thr (4 waves), 32-token slab each -> 2 blocks/CU.
//   h (A operand, 8x reuse) in LDS; W (B operand, no reuse) loaded DIRECTLY
//   to registers (dwordx4, dbuf, depth-2 counted vmcnt). Barrier-free K-loop;
//   bias+residual folded into acc init; XCD-aware batch swizzle.

typedef __attribute__((ext_vector_type(8))) short bf16x8;
typedef __attribute__((ext_vector_type(4))) float f32x4;

#define HPAD 520  // h row stride (elems): row-pair bank alias only (free)
#define VMWAIT(N) asm volatile("s_waitcnt vmcnt(" #N ")" ::: "memory")

static __device__ __forceinline__ uint16_t f2bf(float f) {
  union { float f; uint32_t u; } c; c.f = f;
  uint32_t r = (c.u + 0x7FFFu + ((c.u >> 16) & 1u)) >> 16;
  return (uint16_t)r;
}
static __device__ __forceinline__ float bf2f(uint16_t h) {
  union { uint32_t u; float f; } c; c.u = ((uint32_t)h) << 16;
  return c.f;
}

// ---- merged pre-pass: Wc=Ws+Wr (bf16), Wi/Wo bf16, bc=bs+br ----
__global__ __launch_bounds__(256) void k_prep(
    const float* __restrict__ Ws, const float* __restrict__ Wr,
    const float* __restrict__ Wi, const float* __restrict__ Wo,
    const float* __restrict__ bs, const float* __restrict__ br,
    uint16_t* __restrict__ Wcb, uint16_t* __restrict__ Wib,
    uint16_t* __restrict__ Wob, float* __restrict__ bc) {
  int bid = blockIdx.x, tid = threadIdx.x;
  if (bid < 8192) {                       // combine_w: 2*16*512*512 / 4
    int i = bid * 256 + tid;
    int idx = i * 4;
    int l = idx >> 22;
    int within = idx & (262144 - 1);
    float4 a = *(const float4*)(Ws + l * 262144 + within);
    float4 b = *(const float4*)(Wr + idx);
    ushort4 o;
    o.x = f2bf(a.x + b.x); o.y = f2bf(a.y + b.y);
    o.z = f2bf(a.z + b.z); o.w = f2bf(a.w + b.w);
    ((ushort4*)Wcb)[i] = o;
  } else if (bid < 8320) {                // Wi: 512*256/4
    int i = (bid - 8192) * 256 + tid;
    float4 v = ((const float4*)Wi)[i];
    ushort4 o;
    o.x = f2bf(v.x); o.y = f2bf(v.y); o.z = f2bf(v.z); o.w = f2bf(v.w);
    ((ushort4*)Wib)[i] = o;
  } else if (bid < 8448) {                // Wo: 256*512/4
    int i = (bid - 8320) * 256 + tid;
    float4 v = ((const float4*)Wo)[i];
    ushort4 o;
    o.x = f2bf(v.x); o.y = f2bf(v.y); o.z = f2bf(v.z); o.w = f2bf(v.w);
    ((ushort4*)Wob)[i] = o;
  } else {                                // bc: 2*16*512
    int i = (bid - 8448) * 256 + tid;
    int l = i >> 13, j = i & 511;
    bc[i] = bs[l * 512 + j] + br[i];
  }
}

// ---- one GEMM phase, barrier-free K-loop, B direct-to-register ----
// C[32][NT] = h[32][KK] * W[NT][KK]^T (+bias)(+resid)(relu), in-place into h
// unless F32OUT. 4 waves; wave w owns cols [w*NC, (w+1)*NC), all 32 rows.
template <int NT, int KK, int RESID, int F32OUT>
static __device__ __forceinline__ void gemm_phase(
    const uint16_t* __restrict__ W, const float* __restrict__ bias,
    uint16_t* h, float* __restrict__ gout) {
  constexpr int NSTEP = KK / 32;
  constexpr int NC = NT / 4;          // 128 or 64 cols per wave
  constexpr int NFRAG = NC / 16;      // 8 or 4

  const int tid = threadIdx.x;
  const int lane = tid & 63, wave = tid >> 6;
  const int lr = lane & 15, c0 = lane >> 4;
  const int rb = c0 * 4;

  // B fragment source: lane (lr,c0), frag n, step t ->
  //   W[(wave*NC + n*16 + lr) * KK + t*32 + c0*8], 16B
  const uint16_t* wb = W + (size_t)(wave * NC + lr) * KK + c0 * 8;

  // prologue: issue B(0), B(1) immediately (acc init hides latency)
  bf16x8 b[2][NFRAG];
  #pragma unroll
  for (int n = 0; n < NFRAG; n++)
    b[0][n] = *(const bf16x8*)(wb + (size_t)n * 16 * KK);
  #pragma unroll
  for (int n = 0; n < NFRAG; n++)
    b[1][n] = *(const bf16x8*)(wb + (size_t)n * 16 * KK + 32);

  // acc init = bias (+ residual from h)
  f32x4 acc[2][NFRAG];
  #pragma unroll
  for (int n = 0; n < NFRAG; n++) {
    const int col = wave * NC + n * 16 + lr;
    const float bv = bias[col];
    #pragma unroll
    for (int m = 0; m < 2; m++)
      #pragma unroll
      for (int r = 0; r < 4; r++) {
        float v = bv;
        if constexpr (RESID)
          v += bf2f(h[(size_t)(m * 16 + rb + r) * HPAD + col]);
        acc[m][n][r] = v;
      }
  }

  // A fragments from LDS h, register-double-buffered
  const uint16_t* pA0 = h + (size_t)lr * HPAD + c0 * 8;
  bf16x8 a[2][2];
  #pragma unroll
  for (int m = 0; m < 2; m++)
    a[0][m] = *(const bf16x8*)(pA0 + (size_t)m * 16 * HPAD);

  #pragma unroll
  for (int t = 0; t < NSTEP; t++) {
    const int pp = t & 1;
    // B(t) landed when only B(t+1)'s NFRAG loads remain outstanding
    if (t + 1 < NSTEP) {
      if constexpr (NFRAG == 8) { VMWAIT(8); } else { VMWAIT(4); }
    } else {
      VMWAIT(0);
    }
    if (t + 1 < NSTEP) {       // A prefetch for t+1
      #pragma unroll
      for (int m = 0; m < 2; m++)
        a[pp ^ 1][m] =
            *(const bf16x8*)(pA0 + (size_t)m * 16 * HPAD + (t + 1) * 32);
    }
    #pragma unroll
    for (int m = 0; m < 2; m++)
      #pragma unroll
      for (int n = 0; n < NFRAG; n++)
        acc[m][n] = __builtin_amdgcn_mfma_f32_16x16x32_bf16(
            a[pp][m], b[pp][n], acc[m][n], 0, 0, 0);
    if (t + 2 < NSTEP) {       // refill just-consumed B buffer for t+2
      #pragma unroll
      for (int n = 0; n < NFRAG; n++)
        b[pp][n] = *(const bf16x8*)(wb + (size_t)n * 16 * KK + (t + 2) * 32);
    }
  }

  // ---- epilogue ----
  if constexpr (F32OUT) {
    #pragma unroll
    for (int n = 0; n < NFRAG; n++) {
      const int col = wave * NC + n * 16 + lr;
      #pragma unroll
      for (int m = 0; m < 2; m++)
        #pragma unroll
        for (int r = 0; r < 4; r++)
          gout[(size_t)(m * 16 + rb + r) * 256 + col] = acc[m][n][r];
    }
  } else {
    __syncthreads();  // all waves done reading h
    #pragma unroll
    for (int n = 0; n < NFRAG; n++) {
      const int col = wave * NC + n * 16 + lr;
      #pragma unroll
      for (int m = 0; m < 2; m++)
        #pragma unroll
        for (int r = 0; r < 4; r++)
          h[(size_t)(m * 16 + rb + r) * HPAD + col] =
              f2bf(fmaxf(acc[m][n][r], 0.0f));
    }
    __syncthreads();  // writes visible before next phase reads
  }
}

__global__ __launch_bounds__(256, 2) void k_fused(
    const float* __restrict__ x, const int* __restrict__ route,
    const uint16_t* __restrict__ Wib, const float* __restrict__ bi,
    const uint16_t* __restrict__ Wcb, const float* __restrict__ bcb,
    const uint16_t* __restrict__ Wob, const float* __restrict__ bo,
    float* __restrict__ out) {
  __shared__ uint16_t h[32 * HPAD];     // 33,280 B -> 2 blocks/CU

  const int tid = threadIdx.x;
  // XCD swizzle: XCD r (= bid%8) gets the 8 batches with batch%8==r,
  // 8 slabs each -> per-phase L2 weight set <= 8 experts * 0.5MB = 4MB.
  const int bid = blockIdx.x;
  const int r = bid & 7, q = bid >> 3;      // q: 0..63
  const int batch = (q >> 3) * 8 + r;       // 0..63
  const int bx = batch * 8 + (q & 7);       // slab id 0..511
  const int e = route[batch];

  // stage x slab f32 -> bf16 into h (coalesced float4)
  const float* gx = x + (size_t)bx * 8192;
  #pragma unroll
  for (int j = 0; j < 8; j++) {
    int fi = j * 1024 + tid * 4;
    float4 v = *(const float4*)(gx + fi);
    int row = fi >> 8, c = fi & 255;
    ushort4 o;
    o.x = f2bf(v.x); o.y = f2bf(v.y); o.z = f2bf(v.z); o.w = f2bf(v.w);
    *(ushort4*)(h + (size_t)row * HPAD + c) = o;
  }
  __syncthreads();

  // proj: h = relu(x * Wi^T + bi)            N=512 K=256
  gemm_phase<512, 256, 0, 0>(Wib, bi, h, nullptr);
  // layer 0: h = relu(h*Wc[0,e]^T + bc + h)  N=K=512
  gemm_phase<512, 512, 1, 0>(Wcb + (size_t)e * 262144, bcb + e * 512,
                             h, nullptr);
  // layer 1
  gemm_phase<512, 512, 1, 0>(Wcb + (size_t)(16 + e) * 262144,
                             bcb + (16 + e) * 512, h, nullptr);
  // out: f32 = h * Wo^T + bo                 N=256 K=512
  gemm_phase<256, 512, 0, 1>(Wob, bo, h, out + (size_t)bx * 8192);
}

extern "C" void kernel_launch(void* const* d_in, const int* in_sizes, int n_in,
                              void* d_out, int out_size, void* d_ws, size_t ws_size,
                              hipStream_t stream) {
  const float* x     = (const float*)d_in[0];
  const int*   route = (const int*)d_in[1];
  const float* Wi    = (const float*)d_in[2];
  const float* bi    = (const float*)d_in[3];
  const float* Wr    = (const float*)d_in[4];
  const float* br    = (const float*)d_in[5];
  const float* Ws    = (const float*)d_in[6];
  const float* bs    = (const float*)d_in[7];
  const float* Wo    = (const float*)d_in[8];
  const float* bo    = (const float*)d_in[9];

  char* ws = (char*)d_ws;
  uint16_t* Wib = (uint16_t*)(ws);                  //    262,144 B
  uint16_t* Wcb = (uint16_t*)(ws + 262144);         // 16,777,216 B
  uint16_t* Wob = (uint16_t*)(ws + 17039360);       //    262,144 B
  float*    bc  = (float*)   (ws + 17301504);       //     65,536 B

  k_prep<<<8512, 256, 0, stream>>>(Ws, Wr, Wi, Wo, bs, br,
                                   Wcb, Wib, Wob, bc);
  k_fused<<<512, 256, 0, stream>>>(x, route, Wib, bi, Wcb, bc, Wob, bo,
                                   (float*)d_out);
}

// Round 7
// 50.514 us; speedup vs baseline: 2.0758x; 2.0758x over previous
//
#include <hip/hip_runtime.h>
#include <hip/hip_bf16.h>
#include <stdint.h>

// MoEDecoder: B=64,T=256,IN=256,HID=512,OUT=256,L=2,E=16,S=1
// Fused persistent kernel, R7 (= R5 minus in-loop barriers):
//   grid 256 x 512 thr (8 waves), 64-token slab, h in LDS (in-place update).
//   Each wave stages ITS OWN 64 W-rows via global_load_lds (private LDS dbuf,
//   depth-2, counted vmcnt) -> NO cross-wave deps in K-loop -> no barriers;
//   waves self-pace and the SIMD scheduler overlaps them (2 waves/SIMD).
//   setprio(1) around MFMA cluster. Barriers only at phase boundaries.
//   bias+resid folded into acc init; XCD-aware batch swizzle (L2-fit).

typedef __attribute__((ext_vector_type(8))) short bf16x8;
typedef __attribute__((ext_vector_type(4))) float f32x4;

#define HPAD 520  // h row stride (elems): 1040B rows, b128 reads ~min-cost
#define VMWAIT(N) asm volatile("s_waitcnt vmcnt(" #N ")" ::: "memory")

static __device__ __forceinline__ uint16_t f2bf(float f) {
  union { float f; uint32_t u; } c; c.f = f;
  uint32_t r = (c.u + 0x7FFFu + ((c.u >> 16) & 1u)) >> 16;
  return (uint16_t)r;
}
static __device__ __forceinline__ float bf2f(uint16_t h) {
  union { uint32_t u; float f; } c; c.u = ((uint32_t)h) << 16;
  return c.f;
}

static __device__ __forceinline__ void glds16(const uint16_t* g, uint16_t* l) {
  __builtin_amdgcn_global_load_lds(
      (const __attribute__((address_space(1))) uint32_t*)g,
      (__attribute__((address_space(3))) uint32_t*)l, 16, 0, 0);
}

// ---- merged pre-pass: Wc=Ws+Wr (bf16), Wi/Wo bf16, bc=bs+br ----
__global__ __launch_bounds__(256) void k_prep(
    const float* __restrict__ Ws, const float* __restrict__ Wr,
    const float* __restrict__ Wi, const float* __restrict__ Wo,
    const float* __restrict__ bs, const float* __restrict__ br,
    uint16_t* __restrict__ Wcb, uint16_t* __restrict__ Wib,
    uint16_t* __restrict__ Wob, float* __restrict__ bc) {
  int bid = blockIdx.x, tid = threadIdx.x;
  if (bid < 8192) {                       // combine_w: 2*16*512*512 / 4
    int i = bid * 256 + tid;
    int idx = i * 4;
    int l = idx >> 22;
    int within = idx & (262144 - 1);
    float4 a = *(const float4*)(Ws + l * 262144 + within);
    float4 b = *(const float4*)(Wr + idx);
    ushort4 o;
    o.x = f2bf(a.x + b.x); o.y = f2bf(a.y + b.y);
    o.z = f2bf(a.z + b.z); o.w = f2bf(a.w + b.w);
    ((ushort4*)Wcb)[i] = o;
  } else if (bid < 8320) {                // Wi: 512*256/4
    int i = (bid - 8192) * 256 + tid;
    float4 v = ((const float4*)Wi)[i];
    ushort4 o;
    o.x = f2bf(v.x); o.y = f2bf(v.y); o.z = f2bf(v.z); o.w = f2bf(v.w);
    ((ushort4*)Wib)[i] = o;
  } else if (bid < 8448) {                // Wo: 256*512/4
    int i = (bid - 8320) * 256 + tid;
    float4 v = ((const float4*)Wo)[i];
    ushort4 o;
    o.x = f2bf(v.x); o.y = f2bf(v.y); o.z = f2bf(v.z); o.w = f2bf(v.w);
    ((ushort4*)Wob)[i] = o;
  } else {                                // bc: 2*16*512
    int i = (bid - 8448) * 256 + tid;
    int l = i >> 13, j = i & 511;
    bc[i] = bs[l * 512 + j] + br[i];
  }
}

// ---- one GEMM phase, barrier-free self-paced K-loop ----
// C[64][NT] = h[64][KK] * W[NT][KK]^T (+bias)(+resid)(relu), in-place into h
// unless F32OUT. 8 waves; wave w owns cols [w*NC, (w+1)*NC), all 64 rows.
// Wave stages its own W rows into its private LDS dbuf (counted vmcnt).
template <int NT, int KK, int RESID, int F32OUT>
static __device__ __forceinline__ void gemm_phase(
    const uint16_t* __restrict__ W, const float* __restrict__ bias,
    uint16_t* h, float* __restrict__ gout, uint16_t* lS) {
  constexpr int NSTEP = KK / 32;
  constexpr int NC = NT / 8;          // 64 or 32 cols per wave
  constexpr int NFRAG = NC / 16;      // 4 or 2
  constexpr int LPS = NFRAG;          // glds (1KB each) per stage

  const int tid = threadIdx.x;
  const int lane = tid & 63, wave = tid >> 6;
  const int lr = lane & 15, c0 = lane >> 4;
  const int rb = c0 * 4;

  uint16_t* lw = lS + wave * 4096;    // private 8KB region (2 bufs)

  // staging: lane l covers local row j*16 + l/4, 16B chunk; source chunk
  // XOR-swizzled so the ds_read side is spread (verified R4/R5).
  const int srow = lane >> 2;
  const int sch = (lane & 3) ^ ((lane >> 3) & 3);
  const uint16_t* wbase = W + (size_t)(wave * NC + srow) * KK + sch * 8;

  auto stage = [&](int buf, int t) {
    #pragma unroll
    for (int j = 0; j < LPS; j++)
      glds16(wbase + (size_t)j * 16 * KK + t * 32,
             lw + buf * (NC * 32) + j * 512);
  };

  stage(0, 0);
  stage(1, 1);

  // acc init = bias (+ residual from h) — hides under first stage latency
  f32x4 acc[4][NFRAG];
  #pragma unroll
  for (int n = 0; n < NFRAG; n++) {
    const int col = wave * NC + n * 16 + lr;
    const float bv = bias[col];
    #pragma unroll
    for (int m = 0; m < 4; m++)
      #pragma unroll
      for (int r = 0; r < 4; r++) {
        float v = bv;
        if constexpr (RESID)
          v += bf2f(h[(size_t)(m * 16 + rb + r) * HPAD + col]);
        acc[m][n][r] = v;
      }
  }

  const int bch = c0 ^ ((lr >> 1) & 3);
  const uint16_t* pB0 = lw + lr * 32 + bch * 8;
  const uint16_t* pA0 = h + (size_t)lr * HPAD + c0 * 8;

  auto step_body = [&](int t) {
    const uint16_t* pB = pB0 + (t & 1) * (NC * 32);
    const int kb = t * 32;
    bf16x8 a[4], b[NFRAG];
    #pragma unroll
    for (int m = 0; m < 4; m++)
      a[m] = *(const bf16x8*)(pA0 + (size_t)m * 16 * HPAD + kb);
    #pragma unroll
    for (int n = 0; n < NFRAG; n++)
      b[n] = *(const bf16x8*)(pB + n * 512);
    __builtin_amdgcn_s_setprio(1);
    #pragma unroll
    for (int m = 0; m < 4; m++)
      #pragma unroll
      for (int n = 0; n < NFRAG; n++)
        acc[m][n] = __builtin_amdgcn_mfma_f32_16x16x32_bf16(a[m], b[n],
                                                            acc[m][n], 0, 0, 0);
    __builtin_amdgcn_s_setprio(0);
  };

  // steady state: at iter t, newest in-flight is stage(t+1) -> VMWAIT(LPS)
  // guarantees stage(t) landed. Refill issued AFTER MFMA consumed the buf
  // being overwritten (race-free: lgkm wait before MFMA retires the reads).
  for (int t = 0; t < NSTEP - 1; t++) {
    if constexpr (LPS == 4) { VMWAIT(4); } else { VMWAIT(2); }
    step_body(t);
    if (t + 2 < NSTEP) stage(t & 1, t + 2);
  }
  VMWAIT(0);                       // last buffer: nothing newer in flight
  step_body(NSTEP - 1);

  // ---- epilogue ----
  if constexpr (F32OUT) {
    #pragma unroll
    for (int n = 0; n < NFRAG; n++) {
      const int col = wave * NC + n * 16 + lr;
      #pragma unroll
      for (int m = 0; m < 4; m++)
        #pragma unroll
        for (int r = 0; r < 4; r++)
          gout[(size_t)(m * 16 + rb + r) * 256 + col] = acc[m][n][r];
    }
  } else {
    __syncthreads();  // all waves done reading h (A + resid)
    #pragma unroll
    for (int n = 0; n < NFRAG; n++) {
      const int col = wave * NC + n * 16 + lr;
      #pragma unroll
      for (int m = 0; m < 4; m++)
        #pragma unroll
        for (int r = 0; r < 4; r++)
          h[(size_t)(m * 16 + rb + r) * HPAD + col] =
              f2bf(fmaxf(acc[m][n][r], 0.0f));
    }
    __syncthreads();  // writes visible before next phase reads
  }
}

__global__ __launch_bounds__(512) void k_fused(
    const float* __restrict__ x, const int* __restrict__ route,
    const uint16_t* __restrict__ Wib, const float* __restrict__ bi,
    const uint16_t* __restrict__ Wcb, const float* __restrict__ bcb,
    const uint16_t* __restrict__ Wob, const float* __restrict__ bo,
    float* __restrict__ out) {
  __shared__ uint16_t h[64 * HPAD];     // 66,560 B
  __shared__ uint16_t lS[8 * 4096];     // 65,536 B   total 132,096 B

  const int tid = threadIdx.x;
  // XCD swizzle: XCD r (= bid%8) gets the 8 batches with batch%8==r
  // (4 slabs each) -> per-phase L2 weight set <= 4MB (fits).
  const int bid = blockIdx.x;
  const int r = bid & 7, q = bid >> 3;
  const int batch = (q >> 2) * 8 + r;   // 0..63
  const int bx = batch * 4 + (q & 3);   // slab id 0..255
  const int e = route[batch];

  // stage x slab f32 -> bf16 into h (coalesced float4)
  const float* gx = x + (size_t)bx * 16384;
  #pragma unroll
  for (int j = 0; j < 8; j++) {
    int fi = j * 2048 + tid * 4;
    float4 v = *(const float4*)(gx + fi);
    int row = fi >> 8, c = fi & 255;
    ushort4 o;
    o.x = f2bf(v.x); o.y = f2bf(v.y); o.z = f2bf(v.z); o.w = f2bf(v.w);
    *(ushort4*)(h + (size_t)row * HPAD + c) = o;
  }
  __syncthreads();

  // proj: h = relu(x * Wi^T + bi)            N=512 K=256
  gemm_phase<512, 256, 0, 0>(Wib, bi, h, nullptr, lS);
  // layer 0: h = relu(h*Wc[0,e]^T + bc + h)  N=K=512
  gemm_phase<512, 512, 1, 0>(Wcb + (size_t)e * 262144, bcb + e * 512,
                             h, nullptr, lS);
  // layer 1
  gemm_phase<512, 512, 1, 0>(Wcb + (size_t)(16 + e) * 262144,
                             bcb + (16 + e) * 512, h, nullptr, lS);
  // out: f32 = h * Wo^T + bo                 N=256 K=512
  gemm_phase<256, 512, 0, 1>(Wob, bo, h, out + (size_t)bx * 16384, lS);
}

extern "C" void kernel_launch(void* const* d_in, const int* in_sizes, int n_in,
                              void* d_out, int out_size, void* d_ws, size_t ws_size,
                              hipStream_t stream) {
  const float* x     = (const float*)d_in[0];
  const int*   route = (const int*)d_in[1];
  const float* Wi    = (const float*)d_in[2];
  const float* bi    = (const float*)d_in[3];
  const float* Wr    = (const float*)d_in[4];
  const float* br    = (const float*)d_in[5];
  const float* Ws    = (const float*)d_in[6];
  const float* bs    = (const float*)d_in[7];
  const float* Wo    = (const float*)d_in[8];
  const float* bo    = (const float*)d_in[9];

  char* ws = (char*)d_ws;
  uint16_t* Wib = (uint16_t*)(ws);                  //    262,144 B
  uint16_t* Wcb = (uint16_t*)(ws + 262144);         // 16,777,216 B
  uint16_t* Wob = (uint16_t*)(ws + 17039360);       //    262,144 B
  float*    bc  = (float*)   (ws + 17301504);       //     65,536 B

  k_prep<<<8512, 256, 0, stream>>>(Ws, Wr, Wi, Wo, bs, br,
                                   Wcb, Wib, Wob, bc);
  k_fused<<<256, 512, 0, stream>>>(x, route, Wib, bi, Wcb, bc, Wob, bo,
                                   (float*)d_out);
}

// Round 9
// 50.400 us; speedup vs baseline: 2.0805x; 1.0023x over previous
//
#include <hip/hip_runtime.h>
#include <hip/hip_bf16.h>
#include <stdint.h>

// MoEDecoder: B=64,T=256,IN=256,HID=512,OUT=256,L=2,E=16,S=1
// Fused persistent kernel, R8 = R7 + deep pipeline:
//   grid 256 x 512 thr (8 waves), 64-token slab, h in LDS (in-place update).
//   Wave-private weight staging (global_load_lds dbuf, counted vmcnt, no
//   in-loop barriers). Register-double-buffered fragments — ds_read for
//   step t+1 issued between VMWAIT and MFMA(t); glds for t+2 issued BEFORE
//   the wait. MFMAs never wait on lgkm; stages get ~2 iters of L2 cover.

typedef __attribute__((ext_vector_type(8))) short bf16x8;
typedef __attribute__((ext_vector_type(4))) float f32x4;

#define HPAD 520  // h row stride (elems)
#define VMWAIT(N) asm volatile("s_waitcnt vmcnt(" #N ")" ::: "memory")

static __device__ __forceinline__ uint16_t f2bf(float f) {
  union { float f; uint32_t u; } c; c.f = f;
  uint32_t r = (c.u + 0x7FFFu + ((c.u >> 16) & 1u)) >> 16;
  return (uint16_t)r;
}
static __device__ __forceinline__ float bf2f(uint16_t h) {
  union { uint32_t u; float f; } c; c.u = ((uint32_t)h) << 16;
  return c.f;
}

static __device__ __forceinline__ void glds16(const uint16_t* g, uint16_t* l) {
  __builtin_amdgcn_global_load_lds(
      (const __attribute__((address_space(1))) uint32_t*)g,
      (__attribute__((address_space(3))) uint32_t*)l, 16, 0, 0);
}

// ---- merged pre-pass: Wc=Ws+Wr (bf16), Wi/Wo bf16, bc=bs+br ----
__global__ __launch_bounds__(256) void k_prep(
    const float* __restrict__ Ws, const float* __restrict__ Wr,
    const float* __restrict__ Wi, const float* __restrict__ Wo,
    const float* __restrict__ bs, const float* __restrict__ br,
    uint16_t* __restrict__ Wcb, uint16_t* __restrict__ Wib,
    uint16_t* __restrict__ Wob, float* __restrict__ bc) {
  int bid = blockIdx.x, tid = threadIdx.x;
  if (bid < 8192) {                       // combine_w: 2*16*512*512 / 4
    int i = bid * 256 + tid;
    int idx = i * 4;
    int l = idx >> 22;
    int within = idx & (262144 - 1);
    float4 a = *(const float4*)(Ws + l * 262144 + within);
    float4 b = *(const float4*)(Wr + idx);
    ushort4 o;
    o.x = f2bf(a.x + b.x); o.y = f2bf(a.y + b.y);
    o.z = f2bf(a.z + b.z); o.w = f2bf(a.w + b.w);
    ((ushort4*)Wcb)[i] = o;
  } else if (bid < 8320) {                // Wi: 512*256/4
    int i = (bid - 8192) * 256 + tid;
    float4 v = ((const float4*)Wi)[i];
    ushort4 o;
    o.x = f2bf(v.x); o.y = f2bf(v.y); o.z = f2bf(v.z); o.w = f2bf(v.w);
    ((ushort4*)Wib)[i] = o;
  } else if (bid < 8448) {                // Wo: 256*512/4
    int i = (bid - 8320) * 256 + tid;
    float4 v = ((const float4*)Wo)[i];
    ushort4 o;
    o.x = f2bf(v.x); o.y = f2bf(v.y); o.z = f2bf(v.z); o.w = f2bf(v.w);
    ((ushort4*)Wob)[i] = o;
  } else {                                // bc: 2*16*512
    int i = (bid - 8448) * 256 + tid;
    int l = i >> 13, j = i & 511;
    bc[i] = bs[l * 512 + j] + br[i];
  }
}

// ---- one GEMM phase, deep-pipelined barrier-free K-loop ----
// C[64][NT] = h[64][KK] * W[NT][KK]^T (+bias)(+resid)(relu), in-place into h
// unless F32OUT. 8 waves; wave w owns cols [w*NC,(w+1)*NC), all 64 rows.
template <int NT, int KK, int RESID, int F32OUT>
static __device__ __forceinline__ void gemm_phase(
    const uint16_t* __restrict__ W, const float* __restrict__ bias,
    uint16_t* h, float* __restrict__ gout, uint16_t* lS) {
  constexpr int NSTEP = KK / 32;
  constexpr int NC = NT / 8;          // 64 or 32 cols per wave
  constexpr int NFRAG = NC / 16;      // 4 or 2
  constexpr int LPS = NFRAG;          // glds (1KB each) per stage

  const int tid = threadIdx.x;
  const int lane = tid & 63, wave = tid >> 6;
  const int lr = lane & 15, c0 = lane >> 4;
  const int rb = c0 * 4;

  uint16_t* lw = lS + wave * 4096;    // private 8KB region (2 bufs)

  // staging: lane l covers local row l/4, 16B chunk; source chunk
  // XOR-swizzled so the ds_read side is spread (verified R4/R5).
  const int srow = lane >> 2;
  const int sch = (lane & 3) ^ ((lane >> 3) & 3);
  const uint16_t* wbase = W + (size_t)(wave * NC + srow) * KK + sch * 8;

  auto stage = [&](int buf, int t) {
    #pragma unroll
    for (int j = 0; j < LPS; j++)
      glds16(wbase + (size_t)j * 16 * KK + t * 32,
             lw + buf * (NC * 32) + j * 512);
  };

  stage(0, 0);
  stage(1, 1);

  // acc init = bias (+ residual from h) — hides under first stage latency
  f32x4 acc[4][NFRAG];
  #pragma unroll
  for (int n = 0; n < NFRAG; n++) {
    const int col = wave * NC + n * 16 + lr;
    const float bv = bias[col];
    #pragma unroll
    for (int m = 0; m < 4; m++)
      #pragma unroll
      for (int r = 0; r < 4; r++) {
        float v = bv;
        if constexpr (RESID)
          v += bf2f(h[(size_t)(m * 16 + rb + r) * HPAD + col]);
        acc[m][n][r] = v;
      }
  }

  const int bch = c0 ^ ((lr >> 1) & 3);
  const uint16_t* pB0 = lw + lr * 32 + bch * 8;
  const uint16_t* pA0 = h + (size_t)lr * HPAD + c0 * 8;

  bf16x8 a[2][4], b[2][NFRAG];

  auto frag_read = [&](int slot, int t) {   // slot, t compile-time static
    const uint16_t* pB = pB0 + (t & 1) * (NC * 32);
    #pragma unroll
    for (int m = 0; m < 4; m++)
      a[slot][m] = *(const bf16x8*)(pA0 + (size_t)m * 16 * HPAD + t * 32);
    #pragma unroll
    for (int n = 0; n < NFRAG; n++)
      b[slot][n] = *(const bf16x8*)(pB + n * 512);
  };

  if constexpr (LPS == 4) { VMWAIT(4); } else { VMWAIT(2); }  // stage(0) done
  frag_read(0, 0);

  #pragma unroll
  for (int t = 0; t < NSTEP; t++) {
    const int cur = t & 1, nxt = cur ^ 1;
    if (t + 2 < NSTEP) stage(cur, t + 2);   // early issue; writes buf[cur],
                                            // regs already hold its data
    if (t + 1 < NSTEP) {
      if (t + 2 < NSTEP) {
        if constexpr (LPS == 4) { VMWAIT(4); } else { VMWAIT(2); }
      } else {
        VMWAIT(0);
      }
      frag_read(nxt, t + 1);      // ds_read latency hides under MFMA(t)
    }
    __builtin_amdgcn_s_setprio(1);
    #pragma unroll
    for (int m = 0; m < 4; m++)
      #pragma unroll
      for (int n = 0; n < NFRAG; n++)
        acc[m][n] = __builtin_amdgcn_mfma_f32_16x16x32_bf16(
            a[cur][m], b[cur][n], acc[m][n], 0, 0, 0);
    __builtin_amdgcn_s_setprio(0);
  }

  // ---- epilogue ----
  if constexpr (F32OUT) {
    #pragma unroll
    for (int n = 0; n < NFRAG; n++) {
      const int col = wave * NC + n * 16 + lr;
      #pragma unroll
      for (int m = 0; m < 4; m++)
        #pragma unroll
        for (int r = 0; r < 4; r++)
          gout[(size_t)(m * 16 + rb + r) * 256 + col] = acc[m][n][r];
    }
  } else {
    __syncthreads();  // all waves done reading h (A + resid)
    #pragma unroll
    for (int n = 0; n < NFRAG; n++) {
      const int col = wave * NC + n * 16 + lr;
      #pragma unroll
      for (int m = 0; m < 4; m++)
        #pragma unroll
        for (int r = 0; r < 4; r++)
          h[(size_t)(m * 16 + rb + r) * HPAD + col] =
              f2bf(fmaxf(acc[m][n][r], 0.0f));
    }
    __syncthreads();  // writes visible before next phase reads
  }
}

__global__ __launch_bounds__(512) void k_fused(
    const float* __restrict__ x, const int* __restrict__ route,
    const uint16_t* __restrict__ Wib, const float* __restrict__ bi,
    const uint16_t* __restrict__ Wcb, const float* __restrict__ bcb,
    const uint16_t* __restrict__ Wob, const float* __restrict__ bo,
    float* __restrict__ out) {
  __shared__ uint16_t h[64 * HPAD];     // 66,560 B
  __shared__ uint16_t lS[8 * 4096];     // 65,536 B   total 132,096 B

  const int tid = threadIdx.x;
  // XCD swizzle: XCD r (= bid%8) gets the 8 batches with batch%8==r
  // (4 slabs each) -> per-phase L2 weight set <= 4MB (fits).
  const int bid = blockIdx.x;
  const int r = bid & 7, q = bid >> 3;
  const int batch = (q >> 2) * 8 + r;   // 0..63
  const int bx = batch * 4 + (q & 3);   // slab id 0..255
  const int e = route[batch];

  // stage x slab f32 -> bf16 into h (coalesced float4)
  const float* gx = x + (size_t)bx * 16384;
  #pragma unroll
  for (int j = 0; j < 8; j++) {
    int fi = j * 2048 + tid * 4;
    float4 v = *(const float4*)(gx + fi);
    int row = fi >> 8, c = fi & 255;
    ushort4 o;
    o.x = f2bf(v.x); o.y = f2bf(v.y); o.z = f2bf(v.z); o.w = f2bf(v.w);
    *(ushort4*)(h + (size_t)row * HPAD + c) = o;
  }
  __syncthreads();

  // proj: h = relu(x * Wi^T + bi)            N=512 K=256
  gemm_phase<512, 256, 0, 0>(Wib, bi, h, nullptr, lS);
  // layer 0: h = relu(h*Wc[0,e]^T + bc + h)  N=K=512
  gemm_phase<512, 512, 1, 0>(Wcb + (size_t)e * 262144, bcb + e * 512,
                             h, nullptr, lS);
  // layer 1
  gemm_phase<512, 512, 1, 0>(Wcb + (size_t)(16 + e) * 262144,
                             bcb + (16 + e) * 512, h, nullptr, lS);
  // out: f32 = h * Wo^T + bo                 N=256 K=512
  gemm_phase<256, 512, 0, 1>(Wob, bo, h, out + (size_t)bx * 16384, lS);
}

extern "C" void kernel_launch(void* const* d_in, const int* in_sizes, int n_in,
                              void* d_out, int out_size, void* d_ws, size_t ws_size,
                              hipStream_t stream) {
  const float* x     = (const float*)d_in[0];
  const int*   route = (const int*)d_in[1];
  const float* Wi    = (const float*)d_in[2];
  const float* bi    = (const float*)d_in[3];
  const float* Wr    = (const float*)d_in[4];
  const float* br    = (const float*)d_in[5];
  const float* Ws    = (const float*)d_in[6];
  const float* bs    = (const float*)d_in[7];
  const float* Wo    = (const float*)d_in[8];
  const float* bo    = (const float*)d_in[9];

  char* ws = (char*)d_ws;
  uint16_t* Wib = (uint16_t*)(ws);                  //    262,144 B
  uint16_t* Wcb = (uint16_t*)(ws + 262144);         // 16,777,216 B
  uint16_t* Wob = (uint16_t*)(ws + 17039360);       //    262,144 B
  float*    bc  = (float*)   (ws + 17301504);       //     65,536 B

  k_prep<<<8512, 256, 0, stream>>>(Ws, Wr, Wi, Wo, bs, br,
                                   Wcb, Wib, Wob, bc);
  k_fused<<<256, 512, 0, stream>>>(x, route, Wib, bi, Wcb, bc, Wob, bo,
                                   (float*)d_out);
}